// Round 2
// baseline (156.234 us; speedup 1.0000x reference)
//
#include <hip/hip_runtime.h>

// Fused voxel-histogram + linear classifier for MI355X.
// x: (1024, 8192, 3) f32 in; W: (40, 512) f32; b: (40,) f32; out: (1024, 40) f32.
// One block per batch element; LDS 512-bin histogram; 4-lane/class epilogue.

#define VR      8
#define BINS    512      // VR^3
#define CLASSES 40
#define NPTS    8192
#define NBATCH  1024

__global__ __launch_bounds__(256, 4) void voxel_cls_kernel(
    const float* __restrict__ x,
    const float* __restrict__ W,
    const float* __restrict__ bias,
    float* __restrict__ out)
{
    __shared__ unsigned int hist[BINS];
    const int t = threadIdx.x;
    const int b = blockIdx.x;

    // zero the histogram (512 entries / 256 threads)
    hist[t]       = 0u;
    hist[t + 256] = 0u;
    __syncthreads();

    // ---- histogram phase ----
    // 8192 points = 2048 groups of 4 points (12 floats = 3 float4, 48B-aligned).
    const float4* px = (const float4*)(x + (size_t)b * NPTS * 3);
    #pragma unroll
    for (int j = 0; j < 8; ++j) {
        const int g = j * 256 + t;           // group index 0..2047
        const float4 A = px[g * 3 + 0];
        const float4 B = px[g * 3 + 1];
        const float4 C = px[g * 3 + 2];

        const float px0[4] = {A.x, A.w, B.z, C.y};
        const float px1[4] = {A.y, B.x, B.w, C.z};
        const float px2[4] = {A.z, B.y, C.x, C.w};

        #pragma unroll
        for (int p = 0; p < 4; ++p) {
            const float vx = px0[p], vy = px1[p], vz = px2[p];
            // validity: all coords in [-2, 2] (reference drops out-of-range points)
            const bool ok = (vx >= -2.f) && (vx <= 2.f) &&
                            (vy >= -2.f) && (vy <= 2.f) &&
                            (vz >= -2.f) && (vz <= 2.f);
            // for valid v: (v+2)*2 in [0,8]; trunc == floor; clamp 8 -> 7 (v == HI)
            const int ix = min((int)((vx + 2.f) * 2.f), VR - 1);
            const int iy = min((int)((vy + 2.f) * 2.f), VR - 1);
            const int iz = min((int)((vz + 2.f) * 2.f), VR - 1);
            if (ok) {
                const int lin = (ix * VR + iy) * VR + iz;
                atomicAdd(&hist[lin], 1u);
            }
        }
    }
    __syncthreads();

    // ---- epilogue: out[b][c] = (1/N) * sum_v hist[v] * W[c][v] + bias[c] ----
    // 4 lanes per class: t = c*4 + s, c in [0,40), s in [0,4).
    if (t < CLASSES * 4) {
        const int c = t >> 2;
        const int s = t & 3;
        const float* Wc = W + c * BINS;
        float acc = 0.f;
        #pragma unroll 8
        for (int i = 0; i < BINS / 4; ++i) {
            const int v = i * 4 + s;         // 4 consecutive LDS addrs -> 4 banks, bcast x16
            acc += (float)hist[v] * Wc[v];
        }
        acc += __shfl_xor(acc, 1);
        acc += __shfl_xor(acc, 2);
        if (s == 0)
            out[b * CLASSES + c] = acc * (1.0f / NPTS) + bias[c];
    }
}

extern "C" void kernel_launch(void* const* d_in, const int* in_sizes, int n_in,
                              void* d_out, int out_size, void* d_ws, size_t ws_size,
                              hipStream_t stream) {
    const float* x    = (const float*)d_in[0];   // (1024, 8192, 3)
    const float* W    = (const float*)d_in[1];   // (40, 512)
    const float* bias = (const float*)d_in[2];   // (40,)
    float* out        = (float*)d_out;           // (1024, 40)

    voxel_cls_kernel<<<NBATCH, 256, 0, stream>>>(x, W, bias, out);
}

// Round 3
// 154.871 us; speedup vs baseline: 1.0088x; 1.0088x over previous
//
#include <hip/hip_runtime.h>

// Fused voxel-histogram + linear classifier for MI355X (gfx950).
// x: (1024, 8192, 3) f32; W: (40, 512) f32; b: (40,) f32; out: (1024, 40) f32.
// v2: 512 threads/block (1024 blocks -> 32 waves/CU, the HW max), bounded
// unroll to keep VGPR <= 64 (__launch_bounds__(512,8)), fabs-based validity.

#define VR      8
#define BINS    512      // VR^3
#define CLASSES 40
#define NPTS    8192
#define THREADS 512
#define NGROUPS 4        // 16 pts/thread = 4 groups of 4 points (3 float4 each)

__global__ __launch_bounds__(THREADS, 8) void voxel_cls_kernel(
    const float* __restrict__ x,
    const float* __restrict__ W,
    const float* __restrict__ bias,
    float* __restrict__ out)
{
    __shared__ unsigned int hist[BINS];
    const int t = threadIdx.x;
    const int b = blockIdx.x;

    // zero the histogram (512 entries / 512 threads)
    hist[t] = 0u;
    __syncthreads();

    // ---- histogram phase ----
    // 8192 points = 2048 groups of 4 points (12 floats = 3 float4, 48B-aligned).
    // group id = g*512 + t; bounded unroll keeps <=6 float4 in flight.
    const float4* px = (const float4*)(x + (size_t)b * NPTS * 3);
    #pragma unroll 2
    for (int g = 0; g < NGROUPS; ++g) {
        const int base = (g * THREADS + t) * 3;
        const float4 A = px[base + 0];
        const float4 B = px[base + 1];
        const float4 C = px[base + 2];

        const float qx[4] = {A.x, A.w, B.z, C.y};
        const float qy[4] = {A.y, B.x, B.w, C.z};
        const float qz[4] = {A.z, B.y, C.x, C.w};

        #pragma unroll
        for (int p = 0; p < 4; ++p) {
            const float vx = qx[p], vy = qy[p], vz = qz[p];
            // validity: all coords in [-2,2]; fabs is a free input modifier
            const bool ok = (__builtin_fabsf(vx) <= 2.f) &&
                            (__builtin_fabsf(vy) <= 2.f) &&
                            (__builtin_fabsf(vz) <= 2.f);
            // exact same rounding as reference: (v+2)*2, trunc(==floor, arg>=0),
            // clamp 8 -> 7 (v == HI in last bin)
            const int ix = min((int)((vx + 2.f) * 2.f), VR - 1);
            const int iy = min((int)((vy + 2.f) * 2.f), VR - 1);
            const int iz = min((int)((vz + 2.f) * 2.f), VR - 1);
            if (ok) {
                const int lin = (ix * VR + iy) * VR + iz;
                atomicAdd(&hist[lin], 1u);
            }
        }
    }
    __syncthreads();

    // ---- epilogue (identical math to the passing v1 kernel) ----
    // 4 lanes per class: t = c*4 + s, c in [0,40), s in [0,4).
    if (t < CLASSES * 4) {
        const int c = t >> 2;
        const int s = t & 3;
        const float* Wc = W + c * BINS;
        float acc = 0.f;
        #pragma unroll 8
        for (int i = 0; i < BINS / 4; ++i) {
            const int v = i * 4 + s;
            acc += (float)hist[v] * Wc[v];
        }
        acc += __shfl_xor(acc, 1);
        acc += __shfl_xor(acc, 2);
        if (s == 0)
            out[b * CLASSES + c] = acc * (1.0f / NPTS) + bias[c];
    }
}

extern "C" void kernel_launch(void* const* d_in, const int* in_sizes, int n_in,
                              void* d_out, int out_size, void* d_ws, size_t ws_size,
                              hipStream_t stream) {
    const float* x    = (const float*)d_in[0];   // (1024, 8192, 3)
    const float* W    = (const float*)d_in[1];   // (40, 512)
    const float* bias = (const float*)d_in[2];   // (40,)
    float* out        = (float*)d_out;           // (1024, 40)

    const int nbatch = in_sizes[0] / (NPTS * 3); // 1024
    voxel_cls_kernel<<<nbatch, THREADS, 0, stream>>>(x, W, bias, out);
}